// Round 13
// baseline (3737.286 us; speedup 1.0000x reference)
//
#include <hip/hip_runtime.h>
#include <stdint.h>

typedef unsigned int uint32;
typedef unsigned short u16;
typedef unsigned char u8;
typedef __attribute__((ext_vector_type(8))) int i32x8;      // 32B MFMA A/B frag
typedef __attribute__((ext_vector_type(16))) float f32x16;  // 32x32 MFMA C/D frag

#define HASH_BITS 19
#define TABLE_SZ (1u << HASH_BITS)
#define HMASK (TABLE_SZ - 1u)
#define PI_D 3.141592653589793
#define NPTS 131072
#define NWB4 (4 * 512 * 512)          // fp8 bytes for W2..W5 = exactly 1 MiB

// MX-scaled MFMA as plain fp8 GEMM: fmt 0 = e4m3, scale bytes 0x7F = 2^0 = 1.0
#define MFMA64(A, B, C) __builtin_amdgcn_mfma_scale_f32_32x32x64_f8f6f4( \
    (A), (B), (C), 0, 0, 0, 0x7F7F7F7F, 0, 0x7F7F7F7F)

__device__ __forceinline__ u8 f2fp8(float f) {
    int r = __builtin_amdgcn_cvt_pk_fp8_f32(f, f, 0, false);
    return (u8)(r & 0xFF);
}

__device__ const float g_res[16] = {16.f,20.f,25.f,32.f,40.f,50.f,64.f,80.f,
                                    101.f,128.f,161.f,203.f,256.f,322.f,406.f,512.f};

// W2..W5 -> fp8, tiled for 32x32x64 A-frags (unchanged from R12: global loads
// are coalesced; no bank-conflict concern on the global path).
__global__ void prep_weights(const float* __restrict__ W2, const float* __restrict__ W3,
                             const float* __restrict__ W4, const float* __restrict__ W5,
                             u8* __restrict__ wt8) {
    int pid = blockIdx.x * 256 + threadIdx.x;
    int e = pid * 2;                          // even element index
    if (e < NWB4) {
        int m = e >> 18;
        int rem = e & 262143;
        int n = rem >> 9, k = rem & 511;      // k even
        const float* W = (m == 0) ? W2 : (m == 1) ? W3 : (m == 2) ? W4 : W5;
        float v0 = W[k * 512 + n], v1 = W[(k + 1) * 512 + n];
        int g32 = n >> 5, l = (n & 31) + (((k >> 5) & 1) << 5), kk = k >> 6, j = k & 31;
        int dst = m * 262144 + g32 * 16384 + kk * 2048 + l * 32 + j;
        int pk = __builtin_amdgcn_cvt_pk_fp8_f32(v0, v1, 0, false);
        *(u16*)(wt8 + dst) = (u16)(pk & 0xFFFF);
    }
}

__global__ void mask_kernel(const float* __restrict__ x, float* __restrict__ mout, int B) {
    int i = blockIdx.x * 256 + threadIdx.x;
    if (i >= B) return;
    constexpr float bmin[4] = {0.0f, (float)(-PI_D), (float)(0.5 * PI_D), (float)(-0.85 * PI_D)};
    constexpr float bmax[4] = {(float)(PI_D), (float)(PI_D), (float)(0.85 * PI_D), (float)(-0.5 * PI_D)};
    float4 v = ((const float4*)x)[i];
    bool ok = (v.x >= bmin[0]) && (v.x <= bmax[0]) &&
              (v.y >= bmin[1]) && (v.y <= bmax[1]) &&
              (v.z >= bmin[2]) && (v.z <= bmax[2]) &&
              (v.w >= bmin[3]) && (v.w <= bmax[3]);
    mout[i] = ok ? 1.0f : 0.0f;
}

// LDS frag addressing (SPLIT-HALF, conflict-free ds_read_b128):
//   element k of point/row r lives at:
//     kunit=k>>6, kh=(k>>5)&1, j16=(k>>4)&1, jb=k&15
//     addr = kunit*2048 + (kh*2+j16)*512 + (r&31)*16 + jb   [+ (r>>5)*16384 for act]
//   A wave's frag read = 2x ds_read_b128 at base / base+512 with base =
//     kunit*2048 + kh*1024 + pl*16  -> lane stride 16B, zero conflicts.
__device__ __forceinline__ i32x8 lds_frag(const u8* buf, int base) {
    uint4 lo = *(const uint4*)&buf[base];
    uint4 hi = *(const uint4*)&buf[base + 512];
    return (i32x8){(int)lo.x, (int)lo.y, (int)lo.z, (int)lo.w,
                   (int)hi.x, (int)hi.y, (int)hi.z, (int)hi.w};
}

__global__ __launch_bounds__(512, 4)
void fused_mlp(const float* __restrict__ x, const float* __restrict__ tables,
               const float* __restrict__ W1, const float* __restrict__ b1,
               const u8* __restrict__ wt8, const float* __restrict__ W6,
               const float* __restrict__ b2, const float* __restrict__ b3,
               const float* __restrict__ b4, const float* __restrict__ b5,
               const float* __restrict__ b6, float* __restrict__ out, int level) {
    __shared__ u8 act[32768];              // fp8 activations, split-half frag layout
    __shared__ u8 w6lds[16384];            // W6 A-frags (n padded 16->32), split-half
    __shared__ float xsh[64 * 4];          // 1KB
    __shared__ float swsh[64 * 17];        // 4.25KB logits -> softmax weights
    __shared__ u8 elds[8192];              // prefetched table corners: 16B/thread

    const int tid = threadIdx.x;
    const int lane = tid & 63;
    const int wv = tid >> 6;               // wave 0..7
    const int pl = lane & 31;
    const int kh = lane >> 5;              // k-half 0/1 within K=64
    const int ptile = blockIdx.x;
    const float res = g_res[level];

    if (tid < 256) xsh[tid] = x[(size_t)ptile * 256 + tid];
    // W6 A-frags, split-half layout:
    // d: kunit=d>>11, r=d&2047, h2=(r>>9)&3 -> kh=h2>>1, j16=h2&1; pln=(r>>4)&31; jb=r&15
    {
        int base = tid * 32;
#pragma unroll
        for (int i = 0; i < 32; ++i) {
            int d = base + i;
            int kunit = d >> 11, r = d & 2047, h2 = (r >> 9) & 3;
            int pln = (r >> 4) & 31, jb = r & 15;
            int k = kunit * 64 + (h2 >> 1) * 32 + (h2 & 1) * 16 + jb;
            w6lds[d] = (pln < 16) ? f2fp8(W6[k * 16 + pln]) : (u8)0;
        }
    }
    __syncthreads();

    // ---- PREFETCH gather corners (depends only on x): issue loads NOW, they
    // land during L1; values parked in 4 VGPRs then stashed to elds after L1.
    float2 e0v, e1v;
    {
        constexpr float bmin[4] = {0.0f, (float)(-PI_D), (float)(0.5 * PI_D), (float)(-0.85 * PI_D)};
        constexpr float bmax[4] = {(float)(PI_D), (float)(PI_D), (float)(0.85 * PI_D), (float)(-0.5 * PI_D)};
        constexpr uint32 primes[4] = {1u, 2654435761u, 805459861u, 3674653429u};
        const int p = tid >> 3;
        const int pr = tid & 7;
        uint32 ca[4], cb[4];
#pragma unroll
        for (int d = 0; d < 4; ++d) {
            float xv = xsh[p * 4 + d];
            float xc = fminf(fmaxf(xv, bmin[d]), bmax[d]);
            float g = (bmax[d] - bmin[d]) / res;
            float t = (xc - bmin[d]) / g;
            int bl = (int)floorf(t);
            ca[d] = (uint32)bl * primes[d];
            cb[d] = (uint32)(bl + 1) * primes[d];
        }
        const float* tb = tables + (size_t)level * TABLE_SZ * 2;
        int v0 = pr * 2, v1 = pr * 2 + 1;
        uint32 h0 = ((v0 & 8) ? cb[0] : ca[0]) ^ ((v0 & 4) ? cb[1] : ca[1]) ^
                    ((v0 & 2) ? cb[2] : ca[2]) ^ ((v0 & 1) ? cb[3] : ca[3]);
        uint32 h1 = ((v1 & 8) ? cb[0] : ca[0]) ^ ((v1 & 4) ? cb[1] : ca[1]) ^
                    ((v1 & 2) ? cb[2] : ca[2]) ^ ((v1 & 1) ? cb[3] : ca[3]);
        e0v = *(const float2*)(tb + (size_t)(h0 & HMASK) * 2);
        e1v = *(const float2*)(tb + (size_t)(h1 & HMASK) * 2);
    }

    f32x16 acc00, acc01, acc10, acc11;

    // ---- layer 1 as one K=64 MFMA step (feat = [res/512, x, 0...], W1 row0 x512)
    {
        f32x16 zc = {0.f,0.f,0.f,0.f,0.f,0.f,0.f,0.f,0.f,0.f,0.f,0.f,0.f,0.f,0.f,0.f};
        float rs = res * (1.0f / 512.0f);
        i32x8 a1[2], bf[2];
#pragma unroll
        for (int ct = 0; ct < 2; ++ct) {
            int n = wv * 64 + ct * 32 + pl;
            uint32 w0 = 0, w1 = 0;
            if (kh == 0) {
                w0 = __builtin_amdgcn_cvt_pk_fp8_f32(W1[n] * 512.0f, W1[512 + n], 0, false);
                w0 = __builtin_amdgcn_cvt_pk_fp8_f32(W1[1024 + n], W1[1536 + n], w0, true);
                w1 = __builtin_amdgcn_cvt_pk_fp8_f32(W1[2048 + n], 0.0f, 0, false);
            }
            a1[ct] = (i32x8){(int)w0, (int)w1, 0, 0, 0, 0, 0, 0};
        }
#pragma unroll
        for (int rt = 0; rt < 2; ++rt) {
            float4 xv = *(const float4*)&xsh[(rt * 32 + pl) * 4];
            uint32 w0 = 0, w1 = 0;
            if (kh == 0) {
                w0 = __builtin_amdgcn_cvt_pk_fp8_f32(rs, xv.x, 0, false);
                w0 = __builtin_amdgcn_cvt_pk_fp8_f32(xv.y, xv.z, w0, true);
                w1 = __builtin_amdgcn_cvt_pk_fp8_f32(xv.w, 0.0f, 0, false);
            }
            bf[rt] = (i32x8){(int)w0, (int)w1, 0, 0, 0, 0, 0, 0};
        }
        acc00 = MFMA64(a1[0], bf[0], zc);
        acc01 = MFMA64(a1[1], bf[0], zc);
        acc10 = MFMA64(a1[0], bf[1], zc);
        acc11 = MFMA64(a1[1], bf[1], zc);
    }

    // epilogue: bias+relu -> act (split-half layout). C/D 32x32: col=lane&31,
    // row = (reg&3) + 8*(reg>>2) + 4*kh. Next-layer k = n:
    //   kunit=wv, kh'=ct, j16=q>>1, jb=(q&1)*8+4*kh
    //   addr = rt*16384 + wv*2048 + (ct*2+(q>>1))*512 + pl*16 + (q&1)*8 + 4*kh
#define EPI(ACC, RT, CT, BIASP) do {                                           \
        int nb = wv * 64 + (CT) * 32;                                          \
        _Pragma("unroll")                                                      \
        for (int q = 0; q < 4; ++q) {                                          \
            int nn = nb + q * 8 + 4 * kh;                                      \
            float4 bv = *(const float4*)&(BIASP)[nn];                          \
            float v0 = fmaxf((ACC)[q * 4 + 0] + bv.x, 0.f);                    \
            float v1 = fmaxf((ACC)[q * 4 + 1] + bv.y, 0.f);                    \
            float v2 = fmaxf((ACC)[q * 4 + 2] + bv.z, 0.f);                    \
            float v3 = fmaxf((ACC)[q * 4 + 3] + bv.w, 0.f);                    \
            uint32 wrd = __builtin_amdgcn_cvt_pk_fp8_f32(v0, v1, 0, false);    \
            wrd = __builtin_amdgcn_cvt_pk_fp8_f32(v2, v3, wrd, true);          \
            *(uint32*)&act[(RT) * 16384 + wv * 2048 + ((CT) * 2 + (q >> 1)) * 512 \
                           + pl * 16 + (q & 1) * 8 + 4 * kh] = wrd;            \
        }                                                                      \
    } while (0)

    EPI(acc00, 0, 0, b1); EPI(acc01, 0, 1, b1);
    EPI(acc10, 1, 0, b1); EPI(acc11, 1, 1, b1);
    // stash prefetched corners (loads have landed under L1's compute)
    *(float4*)&elds[tid * 16] = make_float4(e0v.x, e0v.y, e1v.x, e1v.y);
    __syncthreads();

    // ---- layers 2..5: A = weights (L2-resident panel), B = act (LDS, conflict-free)
#pragma unroll
    for (int ly = 0; ly < 4; ++ly) {
        const float* bias = (ly == 0) ? b2 : (ly == 1) ? b3 : (ly == 2) ? b4 : b5;
        const u8* lyb = wt8 + ly * 262144 + wv * 32768;
        f32x16 n00 = {0.f,0.f,0.f,0.f,0.f,0.f,0.f,0.f,0.f,0.f,0.f,0.f,0.f,0.f,0.f,0.f};
        f32x16 n01 = n00, n10 = n00, n11 = n00;
#pragma unroll
        for (int kk = 0; kk < 8; ++kk) {
            int rbase = kk * 2048 + kh * 1024 + pl * 16;
            i32x8 ba0 = lds_frag(act, rbase);
            i32x8 ba1 = lds_frag(act, 16384 + rbase);
            i32x8 aw0 = *(const i32x8*)&lyb[kk * 2048 + lane * 32];
            i32x8 aw1 = *(const i32x8*)&lyb[16384 + kk * 2048 + lane * 32];
            n00 = MFMA64(aw0, ba0, n00);
            n10 = MFMA64(aw0, ba1, n10);
            n01 = MFMA64(aw1, ba0, n01);
            n11 = MFMA64(aw1, ba1, n11);
        }
        acc00 = n00; acc01 = n01; acc10 = n10; acc11 = n11;
        __syncthreads();   // all waves done reading act
        EPI(acc00, 0, 0, bias); EPI(acc01, 0, 1, bias);
        EPI(acc10, 1, 0, bias); EPI(acc11, 1, 1, bias);
        __syncthreads();
    }

    // ---- layer 6: waves 0,1 (rt = wv), A = W6 frags (LDS), 8 K-steps
    if (wv < 2) {
        f32x16 a6 = {0.f,0.f,0.f,0.f,0.f,0.f,0.f,0.f,0.f,0.f,0.f,0.f,0.f,0.f,0.f,0.f};
#pragma unroll
        for (int kk = 0; kk < 8; ++kk) {
            int rbase = kk * 2048 + kh * 1024 + pl * 16;
            i32x8 aw = lds_frag(w6lds, rbase);
            i32x8 ba = lds_frag(act, wv * 16384 + rbase);
            a6 = MFMA64(aw, ba, a6);
        }
        int pt = wv * 32 + pl;
#pragma unroll
        for (int q = 0; q < 2; ++q) {      // rows n = q*8 + 4*kh + 0..3 (n<16 valid)
            int n0 = q * 8 + 4 * kh;
            float4 bv = *(const float4*)&b6[n0];
            swsh[pt * 17 + n0 + 0] = a6[q * 4 + 0] + bv.x;
            swsh[pt * 17 + n0 + 1] = a6[q * 4 + 1] + bv.y;
            swsh[pt * 17 + n0 + 2] = a6[q * 4 + 2] + bv.z;
            swsh[pt * 17 + n0 + 3] = a6[q * 4 + 3] + bv.w;
        }
    }
    __syncthreads();

    // ---- softmax over 16 (threads 0..63, one point each)
    if (tid < 64) {
        float zv[16];
        float m = -1e30f;
#pragma unroll
        for (int j = 0; j < 16; ++j) { zv[j] = swsh[tid * 17 + j]; m = fmaxf(m, zv[j]); }
        float s = 0.f;
#pragma unroll
        for (int j = 0; j < 16; ++j) { zv[j] = expf(zv[j] - m); s += zv[j]; }
        float inv = 1.0f / s;
#pragma unroll
        for (int j = 0; j < 16; ++j) swsh[tid * 17 + j] = zv[j] * inv;
    }
    __syncthreads();

    // ---- tail: weighted sum of prefetched corners (all values already in LDS)
    {
        const int p = tid >> 3;
        const int pr = tid & 7;
        float4 ev = *(const float4*)&elds[tid * 16];
        float w0 = swsh[p * 17 + pr * 2];
        float w1 = swsh[p * 17 + pr * 2 + 1];
        float s0 = fmaf(w1, ev.z, fmaf(w0, ev.x, 0.f));
        float s1 = fmaf(w1, ev.w, fmaf(w0, ev.y, 0.f));
#pragma unroll
        for (int sft = 1; sft < 8; sft <<= 1) {
            s0 += __shfl_xor(s0, sft, 64);
            s1 += __shfl_xor(s1, sft, 64);
        }
        if (pr == 0) {
            float* o = out + (size_t)(ptile * 64 + p) * 32 + level * 2;
            __builtin_nontemporal_store(s0, o);
            __builtin_nontemporal_store(s1, o + 1);
        }
    }
#undef EPI
}

extern "C" void kernel_launch(void* const* d_in, const int* in_sizes, int n_in,
                              void* d_out, int out_size, void* d_ws, size_t ws_size,
                              hipStream_t stream) {
    const float* x      = (const float*)d_in[0];
    const float* tables = (const float*)d_in[1];
    const float* W1 = (const float*)d_in[2];
    const float* b1 = (const float*)d_in[3];
    const float* W2 = (const float*)d_in[4];
    const float* b2 = (const float*)d_in[5];
    const float* W3 = (const float*)d_in[6];
    const float* b3 = (const float*)d_in[7];
    const float* W4 = (const float*)d_in[8];
    const float* b4 = (const float*)d_in[9];
    const float* W5 = (const float*)d_in[10];
    const float* b5 = (const float*)d_in[11];
    const float* W6 = (const float*)d_in[12];
    const float* b6 = (const float*)d_in[13];

    const int B = in_sizes[0] / 4;          // 131072
    u8* wt8 = (u8*)d_ws;                    // exactly 1 MiB fp8 panel (W2..W5)

    prep_weights<<<(NWB4 / 2 + 255) / 256, 256, 0, stream>>>(W2, W3, W4, W5, wt8);

    for (int level = 0; level < 16; ++level) {
        fused_mlp<<<dim3(NPTS / 64), 512, 0, stream>>>(
            x, tables, W1, b1, wt8, W6, b2, b3, b4, b5, b6, (float*)d_out, level);
    }
    mask_kernel<<<(B + 255) / 256, 256, 0, stream>>>(x, (float*)d_out + (size_t)B * 32, B);
}

// Round 14
// 3266.718 us; speedup vs baseline: 1.1440x; 1.1440x over previous
//
#include <hip/hip_runtime.h>
#include <stdint.h>

typedef unsigned int uint32;
typedef unsigned short u16;
typedef unsigned char u8;
typedef __attribute__((ext_vector_type(8))) int i32x8;      // 32B MFMA A/B frag
typedef __attribute__((ext_vector_type(16))) float f32x16;  // 32x32 MFMA C/D frag

#define HASH_BITS 19
#define TABLE_SZ (1u << HASH_BITS)
#define HMASK (TABLE_SZ - 1u)
#define PI_D 3.141592653589793
#define NPTS 131072
#define NWB4 (4 * 512 * 512)          // fp8 bytes for W2..W5 = exactly 1 MiB

// MX-scaled MFMA as plain fp8 GEMM: fmt 0 = e4m3, scale bytes 0x7F = 2^0 = 1.0
#define MFMA64(A, B, C) __builtin_amdgcn_mfma_scale_f32_32x32x64_f8f6f4( \
    (A), (B), (C), 0, 0, 0, 0x7F7F7F7F, 0, 0x7F7F7F7F)

__device__ __forceinline__ u8 f2fp8(float f) {
    int r = __builtin_amdgcn_cvt_pk_fp8_f32(f, f, 0, false);
    return (u8)(r & 0xFF);
}

__device__ const float g_res[16] = {16.f,20.f,25.f,32.f,40.f,50.f,64.f,80.f,
                                    101.f,128.f,161.f,203.f,256.f,322.f,406.f,512.f};

// W2..W5 -> fp8, tiled for 32x32x64 A-frags (R12 layout; global path is fine).
__global__ void prep_weights(const float* __restrict__ W2, const float* __restrict__ W3,
                             const float* __restrict__ W4, const float* __restrict__ W5,
                             u8* __restrict__ wt8) {
    int pid = blockIdx.x * 256 + threadIdx.x;
    int e = pid * 2;                          // even element index
    if (e < NWB4) {
        int m = e >> 18;
        int rem = e & 262143;
        int n = rem >> 9, k = rem & 511;      // k even
        const float* W = (m == 0) ? W2 : (m == 1) ? W3 : (m == 2) ? W4 : W5;
        float v0 = W[k * 512 + n], v1 = W[(k + 1) * 512 + n];
        int g32 = n >> 5, l = (n & 31) + (((k >> 5) & 1) << 5), kk = k >> 6, j = k & 31;
        int dst = m * 262144 + g32 * 16384 + kk * 2048 + l * 32 + j;
        int pk = __builtin_amdgcn_cvt_pk_fp8_f32(v0, v1, 0, false);
        *(u16*)(wt8 + dst) = (u16)(pk & 0xFFFF);
    }
}

__global__ void mask_kernel(const float* __restrict__ x, float* __restrict__ mout, int B) {
    int i = blockIdx.x * 256 + threadIdx.x;
    if (i >= B) return;
    constexpr float bmin[4] = {0.0f, (float)(-PI_D), (float)(0.5 * PI_D), (float)(-0.85 * PI_D)};
    constexpr float bmax[4] = {(float)(PI_D), (float)(PI_D), (float)(0.85 * PI_D), (float)(-0.5 * PI_D)};
    float4 v = ((const float4*)x)[i];
    bool ok = (v.x >= bmin[0]) && (v.x <= bmax[0]) &&
              (v.y >= bmin[1]) && (v.y <= bmax[1]) &&
              (v.z >= bmin[2]) && (v.z <= bmax[2]) &&
              (v.w >= bmin[3]) && (v.w <= bmax[3]);
    mout[i] = ok ? 1.0f : 0.0f;
}

// LDS frag addressing (SPLIT-HALF, conflict-reduced ds_read_b128):
//   element k of row r: kunit=k>>6, kh=(k>>5)&1, j16=(k>>4)&1, jb=k&15
//   addr = kunit*2048 + (kh*2+j16)*512 + (r&31)*16 + jb  [+ (r>>5)*16384 for act]
//   wave frag read = 2x ds_read_b128 at base / base+512, base = kunit*2048
//   + kh*1024 + pl*16 -> lane stride 16B.
__device__ __forceinline__ i32x8 lds_frag(const u8* buf, int base) {
    uint4 lo = *(const uint4*)&buf[base];
    uint4 hi = *(const uint4*)&buf[base + 512];
    return (i32x8){(int)lo.x, (int)lo.y, (int)lo.z, (int)lo.w,
                   (int)hi.x, (int)hi.y, (int)hi.z, (int)hi.w};
}

__global__ __launch_bounds__(512, 4)
void fused_mlp(const float* __restrict__ x, const float* __restrict__ tables,
               const float* __restrict__ W1, const float* __restrict__ b1,
               const u8* __restrict__ wt8, const float* __restrict__ W6,
               const float* __restrict__ b2, const float* __restrict__ b3,
               const float* __restrict__ b4, const float* __restrict__ b5,
               const float* __restrict__ b6, float* __restrict__ out, int level) {
    __shared__ u8 act[32768];              // fp8 activations, split-half frag layout
    __shared__ u8 w6lds[16384];            // W6 A-frags (n padded 16->32), split-half
    __shared__ float xsh[64 * 4];          // 1KB
    __shared__ float swsh[64 * 17];        // 4.25KB logits -> softmax weights

    const int tid = threadIdx.x;
    const int lane = tid & 63;
    const int wv = tid >> 6;               // wave 0..7
    const int pl = lane & 31;
    const int kh = lane >> 5;              // k-half 0/1 within K=64
    const int ptile = blockIdx.x;
    const float res = g_res[level];

    if (tid < 256) xsh[tid] = x[(size_t)ptile * 256 + tid];
    // W6 A-frags, split-half layout:
    // d: kunit=d>>11, r=d&2047, h2=(r>>9)&3 -> kh=h2>>1, j16=h2&1; pln=(r>>4)&31; jb=r&15
    {
        int base = tid * 32;
#pragma unroll
        for (int i = 0; i < 32; ++i) {
            int d = base + i;
            int kunit = d >> 11, r = d & 2047, h2 = (r >> 9) & 3;
            int pln = (r >> 4) & 31, jb = r & 15;
            int k = kunit * 64 + (h2 >> 1) * 32 + (h2 & 1) * 16 + jb;
            w6lds[d] = (pln < 16) ? f2fp8(W6[k * 16 + pln]) : (u8)0;
        }
    }
    __syncthreads();

    f32x16 acc00, acc01, acc10, acc11;

    // ---- layer 1 as one K=64 MFMA step (feat = [res/512, x, 0...], W1 row0 x512)
    {
        f32x16 zc = {0.f,0.f,0.f,0.f,0.f,0.f,0.f,0.f,0.f,0.f,0.f,0.f,0.f,0.f,0.f,0.f};
        float rs = res * (1.0f / 512.0f);
        i32x8 a1[2], bf[2];
#pragma unroll
        for (int ct = 0; ct < 2; ++ct) {
            int n = wv * 64 + ct * 32 + pl;
            uint32 w0 = 0, w1 = 0;
            if (kh == 0) {
                w0 = __builtin_amdgcn_cvt_pk_fp8_f32(W1[n] * 512.0f, W1[512 + n], 0, false);
                w0 = __builtin_amdgcn_cvt_pk_fp8_f32(W1[1024 + n], W1[1536 + n], w0, true);
                w1 = __builtin_amdgcn_cvt_pk_fp8_f32(W1[2048 + n], 0.0f, 0, false);
            }
            a1[ct] = (i32x8){(int)w0, (int)w1, 0, 0, 0, 0, 0, 0};
        }
#pragma unroll
        for (int rt = 0; rt < 2; ++rt) {
            float4 xv = *(const float4*)&xsh[(rt * 32 + pl) * 4];
            uint32 w0 = 0, w1 = 0;
            if (kh == 0) {
                w0 = __builtin_amdgcn_cvt_pk_fp8_f32(rs, xv.x, 0, false);
                w0 = __builtin_amdgcn_cvt_pk_fp8_f32(xv.y, xv.z, w0, true);
                w1 = __builtin_amdgcn_cvt_pk_fp8_f32(xv.w, 0.0f, 0, false);
            }
            bf[rt] = (i32x8){(int)w0, (int)w1, 0, 0, 0, 0, 0, 0};
        }
        acc00 = MFMA64(a1[0], bf[0], zc);
        acc01 = MFMA64(a1[1], bf[0], zc);
        acc10 = MFMA64(a1[0], bf[1], zc);
        acc11 = MFMA64(a1[1], bf[1], zc);
    }

    // epilogue: bias+relu -> act (split-half layout). C/D 32x32: col=lane&31,
    // row = (reg&3) + 8*(reg>>2) + 4*kh. Next-layer k = n:
    //   addr = rt*16384 + wv*2048 + (ct*2+(q>>1))*512 + pl*16 + (q&1)*8 + 4*kh
#define EPI(ACC, RT, CT, BIASP) do {                                           \
        int nb = wv * 64 + (CT) * 32;                                          \
        _Pragma("unroll")                                                      \
        for (int q = 0; q < 4; ++q) {                                          \
            int nn = nb + q * 8 + 4 * kh;                                      \
            float4 bv = *(const float4*)&(BIASP)[nn];                          \
            float v0 = fmaxf((ACC)[q * 4 + 0] + bv.x, 0.f);                    \
            float v1 = fmaxf((ACC)[q * 4 + 1] + bv.y, 0.f);                    \
            float v2 = fmaxf((ACC)[q * 4 + 2] + bv.z, 0.f);                    \
            float v3 = fmaxf((ACC)[q * 4 + 3] + bv.w, 0.f);                    \
            uint32 wrd = __builtin_amdgcn_cvt_pk_fp8_f32(v0, v1, 0, false);    \
            wrd = __builtin_amdgcn_cvt_pk_fp8_f32(v2, v3, wrd, true);          \
            *(uint32*)&act[(RT) * 16384 + wv * 2048 + ((CT) * 2 + (q >> 1)) * 512 \
                           + pl * 16 + (q & 1) * 8 + 4 * kh] = wrd;            \
        }                                                                      \
    } while (0)

    EPI(acc00, 0, 0, b1); EPI(acc01, 0, 1, b1);
    EPI(acc10, 1, 0, b1); EPI(acc11, 1, 1, b1);
    __syncthreads();

    // ---- layers 2..5: A = weights (L2-resident panel), B = act (LDS)
#pragma unroll
    for (int ly = 0; ly < 4; ++ly) {
        const float* bias = (ly == 0) ? b2 : (ly == 1) ? b3 : (ly == 2) ? b4 : b5;
        const u8* lyb = wt8 + ly * 262144 + wv * 32768;
        f32x16 n00 = {0.f,0.f,0.f,0.f,0.f,0.f,0.f,0.f,0.f,0.f,0.f,0.f,0.f,0.f,0.f,0.f};
        f32x16 n01 = n00, n10 = n00, n11 = n00;
#pragma unroll
        for (int kk = 0; kk < 8; ++kk) {
            int rbase = kk * 2048 + kh * 1024 + pl * 16;
            i32x8 ba0 = lds_frag(act, rbase);
            i32x8 ba1 = lds_frag(act, 16384 + rbase);
            i32x8 aw0 = *(const i32x8*)&lyb[kk * 2048 + lane * 32];
            i32x8 aw1 = *(const i32x8*)&lyb[16384 + kk * 2048 + lane * 32];
            n00 = MFMA64(aw0, ba0, n00);
            n10 = MFMA64(aw0, ba1, n10);
            n01 = MFMA64(aw1, ba0, n01);
            n11 = MFMA64(aw1, ba1, n11);
        }
        acc00 = n00; acc01 = n01; acc10 = n10; acc11 = n11;
        __syncthreads();   // all waves done reading act
        EPI(acc00, 0, 0, bias); EPI(acc01, 0, 1, bias);
        EPI(acc10, 1, 0, bias); EPI(acc11, 1, 1, bias);
        __syncthreads();
    }

    // ---- layer 6: waves 0,1 (rt = wv), A = W6 frags (LDS), 8 K-steps
    if (wv < 2) {
        f32x16 a6 = {0.f,0.f,0.f,0.f,0.f,0.f,0.f,0.f,0.f,0.f,0.f,0.f,0.f,0.f,0.f,0.f};
#pragma unroll
        for (int kk = 0; kk < 8; ++kk) {
            int rbase = kk * 2048 + kh * 1024 + pl * 16;
            i32x8 aw = lds_frag(w6lds, rbase);
            i32x8 ba = lds_frag(act, wv * 16384 + rbase);
            a6 = MFMA64(aw, ba, a6);
        }
        int pt = wv * 32 + pl;
#pragma unroll
        for (int q = 0; q < 2; ++q) {      // rows n = q*8 + 4*kh + 0..3 (n<16 valid)
            int n0 = q * 8 + 4 * kh;
            float4 bv = *(const float4*)&b6[n0];
            swsh[pt * 17 + n0 + 0] = a6[q * 4 + 0] + bv.x;
            swsh[pt * 17 + n0 + 1] = a6[q * 4 + 1] + bv.y;
            swsh[pt * 17 + n0 + 2] = a6[q * 4 + 2] + bv.z;
            swsh[pt * 17 + n0 + 3] = a6[q * 4 + 3] + bv.w;
        }
    }
    __syncthreads();

    // ---- softmax over 16 (threads 0..63, one point each)
    if (tid < 64) {
        float zv[16];
        float m = -1e30f;
#pragma unroll
        for (int j = 0; j < 16; ++j) { zv[j] = swsh[tid * 17 + j]; m = fmaxf(m, zv[j]); }
        float s = 0.f;
#pragma unroll
        for (int j = 0; j < 16; ++j) { zv[j] = expf(zv[j] - m); s += zv[j]; }
        float inv = 1.0f / s;
#pragma unroll
        for (int j = 0; j < 16; ++j) swsh[tid * 17 + j] = zv[j] * inv;
    }
    __syncthreads();

    // ---- hash gather + weighted sum (R12 tail form): 8 threads/point, 2 corners
    {
        constexpr float bmin[4] = {0.0f, (float)(-PI_D), (float)(0.5 * PI_D), (float)(-0.85 * PI_D)};
        constexpr float bmax[4] = {(float)(PI_D), (float)(PI_D), (float)(0.85 * PI_D), (float)(-0.5 * PI_D)};
        constexpr uint32 primes[4] = {1u, 2654435761u, 805459861u, 3674653429u};
        const int p = tid >> 3;
        const int pr = tid & 7;
        uint32 ca[4], cb[4];
#pragma unroll
        for (int d = 0; d < 4; ++d) {
            float xv = xsh[p * 4 + d];
            float xc = fminf(fmaxf(xv, bmin[d]), bmax[d]);
            float g = (bmax[d] - bmin[d]) / res;
            float t = (xc - bmin[d]) / g;
            int bl = (int)floorf(t);
            ca[d] = (uint32)bl * primes[d];
            cb[d] = (uint32)(bl + 1) * primes[d];
        }
        float s0 = 0.f, s1 = 0.f;
        const float* tb = tables + (size_t)level * TABLE_SZ * 2;
#pragma unroll
        for (int vv = 0; vv < 2; ++vv) {
            int v = pr * 2 + vv;
            uint32 h = ((v & 8) ? cb[0] : ca[0]) ^ ((v & 4) ? cb[1] : ca[1]) ^
                       ((v & 2) ? cb[2] : ca[2]) ^ ((v & 1) ? cb[3] : ca[3]);
            float2 e = *(const float2*)(tb + (size_t)(h & HMASK) * 2);
            float wgt = swsh[p * 17 + v];
            s0 = fmaf(wgt, e.x, s0);
            s1 = fmaf(wgt, e.y, s1);
        }
#pragma unroll
        for (int sft = 1; sft < 8; sft <<= 1) {
            s0 += __shfl_xor(s0, sft, 64);
            s1 += __shfl_xor(s1, sft, 64);
        }
        if (pr == 0) {
            float* o = out + (size_t)(ptile * 64 + p) * 32 + level * 2;
            __builtin_nontemporal_store(s0, o);
            __builtin_nontemporal_store(s1, o + 1);
        }
    }
#undef EPI
}

extern "C" void kernel_launch(void* const* d_in, const int* in_sizes, int n_in,
                              void* d_out, int out_size, void* d_ws, size_t ws_size,
                              hipStream_t stream) {
    const float* x      = (const float*)d_in[0];
    const float* tables = (const float*)d_in[1];
    const float* W1 = (const float*)d_in[2];
    const float* b1 = (const float*)d_in[3];
    const float* W2 = (const float*)d_in[4];
    const float* b2 = (const float*)d_in[5];
    const float* W3 = (const float*)d_in[6];
    const float* b3 = (const float*)d_in[7];
    const float* W4 = (const float*)d_in[8];
    const float* b4 = (const float*)d_in[9];
    const float* W5 = (const float*)d_in[10];
    const float* b5 = (const float*)d_in[11];
    const float* W6 = (const float*)d_in[12];
    const float* b6 = (const float*)d_in[13];

    const int B = in_sizes[0] / 4;          // 131072
    u8* wt8 = (u8*)d_ws;                    // exactly 1 MiB fp8 panel (W2..W5)

    prep_weights<<<(NWB4 / 2 + 255) / 256, 256, 0, stream>>>(W2, W3, W4, W5, wt8);

    for (int level = 0; level < 16; ++level) {
        fused_mlp<<<dim3(NPTS / 64), 512, 0, stream>>>(
            x, tables, W1, b1, wt8, W6, b2, b3, b4, b5, b6, (float*)d_out, level);
    }
    mask_kernel<<<(B + 255) / 256, 256, 0, stream>>>(x, (float*)d_out + (size_t)B * 32, B);
}

// Round 15
// 3040.638 us; speedup vs baseline: 1.2291x; 1.0744x over previous
//
#include <hip/hip_runtime.h>
#include <stdint.h>

typedef unsigned int uint32;
typedef unsigned short u16;
typedef unsigned char u8;
typedef __attribute__((ext_vector_type(8))) int i32x8;      // 32B MFMA A/B frag
typedef __attribute__((ext_vector_type(16))) float f32x16;  // 32x32 MFMA C/D frag

#define HASH_BITS 19
#define TABLE_SZ (1u << HASH_BITS)
#define HMASK (TABLE_SZ - 1u)
#define PI_D 3.141592653589793
#define NPTS 131072
#define NWB4 (4 * 512 * 512)          // fp8 bytes for W2..W5 = exactly 1 MiB

// MX-scaled MFMA as plain fp8 GEMM: fmt 0 = e4m3, scale bytes 0x7F = 2^0 = 1.0
#define MFMA64(A, B, C) __builtin_amdgcn_mfma_scale_f32_32x32x64_f8f6f4( \
    (A), (B), (C), 0, 0, 0, 0x7F7F7F7F, 0, 0x7F7F7F7F)

__device__ __forceinline__ u8 f2fp8(float f) {
    int r = __builtin_amdgcn_cvt_pk_fp8_f32(f, f, 0, false);
    return (u8)(r & 0xFF);
}

__device__ const float g_res[16] = {16.f,20.f,25.f,32.f,40.f,50.f,64.f,80.f,
                                    101.f,128.f,161.f,203.f,256.f,322.f,406.f,512.f};

// W2..W5 -> fp8, tiled for 32x32x64 A-frags: for (n-group g32 of 32, kstep kk of 64)
// a 2KB block; byte = lane*32 + j with lane = (n&31) + 32*((k>>5)&1), j = k&31.
__global__ void prep_weights(const float* __restrict__ W2, const float* __restrict__ W3,
                             const float* __restrict__ W4, const float* __restrict__ W5,
                             u8* __restrict__ wt8) {
    int pid = blockIdx.x * 256 + threadIdx.x;
    int e = pid * 2;                          // even element index
    if (e < NWB4) {
        int m = e >> 18;
        int rem = e & 262143;
        int n = rem >> 9, k = rem & 511;      // k even
        const float* W = (m == 0) ? W2 : (m == 1) ? W3 : (m == 2) ? W4 : W5;
        float v0 = W[k * 512 + n], v1 = W[(k + 1) * 512 + n];
        int g32 = n >> 5, l = (n & 31) + (((k >> 5) & 1) << 5), kk = k >> 6, j = k & 31;
        int dst = m * 262144 + g32 * 16384 + kk * 2048 + l * 32 + j;
        int pk = __builtin_amdgcn_cvt_pk_fp8_f32(v0, v1, 0, false);
        *(u16*)(wt8 + dst) = (u16)(pk & 0xFFFF);
    }
}

__global__ void mask_kernel(const float* __restrict__ x, float* __restrict__ mout, int B) {
    int i = blockIdx.x * 256 + threadIdx.x;
    if (i >= B) return;
    constexpr float bmin[4] = {0.0f, (float)(-PI_D), (float)(0.5 * PI_D), (float)(-0.85 * PI_D)};
    constexpr float bmax[4] = {(float)(PI_D), (float)(PI_D), (float)(0.85 * PI_D), (float)(-0.5 * PI_D)};
    float4 v = ((const float4*)x)[i];
    bool ok = (v.x >= bmin[0]) && (v.x <= bmax[0]) &&
              (v.y >= bmin[1]) && (v.y <= bmax[1]) &&
              (v.z >= bmin[2]) && (v.z <= bmax[2]) &&
              (v.w >= bmin[3]) && (v.w <= bmax[3]);
    mout[i] = ok ? 1.0f : 0.0f;
}

// One block = 64 points x 1 level (level = blockIdx.y; x walks fastest so
// co-resident blocks share a level -> table L2 locality preserved).
// Kernel body identical to R12 (best measured: 232us/level, FETCH 21MB).
__global__ __launch_bounds__(512, 4)
void fused_mlp(const float* __restrict__ x, const float* __restrict__ tables,
               const float* __restrict__ W1, const float* __restrict__ b1,
               const u8* __restrict__ wt8, const float* __restrict__ W6,
               const float* __restrict__ b2, const float* __restrict__ b3,
               const float* __restrict__ b4, const float* __restrict__ b5,
               const float* __restrict__ b6, float* __restrict__ out) {
    __shared__ u8 act[32768];              // 32KB fp8 activations, frag-native layout
    __shared__ u8 w6lds[16384];            // 16KB W6 A-frags (n padded 16->32)
    __shared__ float xsh[64 * 4];          // 1KB
    __shared__ float swsh[64 * 17];        // 4.25KB logits -> softmax weights

    const int tid = threadIdx.x;
    const int lane = tid & 63;
    const int wv = tid >> 6;               // wave 0..7
    const int pl = lane & 31;
    const int kh = lane >> 5;              // k-half 0/1 within K=64
    const int ptile = blockIdx.x;
    const int level = blockIdx.y;
    const float res = g_res[level];

    if (tid < 256) xsh[tid] = x[(size_t)ptile * 256 + tid];
    // W6 A-frags: byte d: kk=d>>11, l=(d>>5)&63, j=d&31; n=l&31, k=kk*64+(l>>5)*32+j
    {
        int base = tid * 32;
#pragma unroll
        for (int i = 0; i < 32; ++i) {
            int d = base + i;
            int kk = d >> 11, l = (d >> 5) & 63, j = d & 31;
            int n = l & 31, k = kk * 64 + (l >> 5) * 32 + j;
            w6lds[d] = (n < 16) ? f2fp8(W6[k * 16 + n]) : (u8)0;
        }
    }
    __syncthreads();

    f32x16 acc00, acc01, acc10, acc11;     // [rt(pt-group)][ct(n-group)]

    // ---- layer 1 as one K=64 MFMA step (feat = [res/512, x, 0...], W1 row0 x512)
    {
        f32x16 zc = {0.f,0.f,0.f,0.f,0.f,0.f,0.f,0.f,0.f,0.f,0.f,0.f,0.f,0.f,0.f,0.f};
        float rs = res * (1.0f / 512.0f);
        i32x8 a1[2], bf[2];
#pragma unroll
        for (int ct = 0; ct < 2; ++ct) {
            int n = wv * 64 + ct * 32 + pl;
            uint32 w0 = 0, w1 = 0;
            if (kh == 0) {
                w0 = __builtin_amdgcn_cvt_pk_fp8_f32(W1[n] * 512.0f, W1[512 + n], 0, false);
                w0 = __builtin_amdgcn_cvt_pk_fp8_f32(W1[1024 + n], W1[1536 + n], w0, true);
                w1 = __builtin_amdgcn_cvt_pk_fp8_f32(W1[2048 + n], 0.0f, 0, false);
            }
            a1[ct] = (i32x8){(int)w0, (int)w1, 0, 0, 0, 0, 0, 0};
        }
#pragma unroll
        for (int rt = 0; rt < 2; ++rt) {
            float4 xv = *(const float4*)&xsh[(rt * 32 + pl) * 4];
            uint32 w0 = 0, w1 = 0;
            if (kh == 0) {
                w0 = __builtin_amdgcn_cvt_pk_fp8_f32(rs, xv.x, 0, false);
                w0 = __builtin_amdgcn_cvt_pk_fp8_f32(xv.y, xv.z, w0, true);
                w1 = __builtin_amdgcn_cvt_pk_fp8_f32(xv.w, 0.0f, 0, false);
            }
            bf[rt] = (i32x8){(int)w0, (int)w1, 0, 0, 0, 0, 0, 0};
        }
        acc00 = MFMA64(a1[0], bf[0], zc);
        acc01 = MFMA64(a1[1], bf[0], zc);
        acc10 = MFMA64(a1[0], bf[1], zc);
        acc11 = MFMA64(a1[1], bf[1], zc);
    }

    // epilogue macro: bias+relu -> act (frag-native). C/D 32x32: col=lane&31,
    // row = (reg&3) + 8*(reg>>2) + 4*kh  [verified layout]
#define EPI(ACC, RT, CT, BIASP) do {                                           \
        int nb = wv * 64 + (CT) * 32;                                          \
        _Pragma("unroll")                                                      \
        for (int q = 0; q < 4; ++q) {                                          \
            int nn = nb + q * 8 + 4 * kh;                                      \
            float4 bv = *(const float4*)&(BIASP)[nn];                          \
            float v0 = fmaxf((ACC)[q * 4 + 0] + bv.x, 0.f);                    \
            float v1 = fmaxf((ACC)[q * 4 + 1] + bv.y, 0.f);                    \
            float v2 = fmaxf((ACC)[q * 4 + 2] + bv.z, 0.f);                    \
            float v3 = fmaxf((ACC)[q * 4 + 3] + bv.w, 0.f);                    \
            uint32 wrd = __builtin_amdgcn_cvt_pk_fp8_f32(v0, v1, 0, false);    \
            wrd = __builtin_amdgcn_cvt_pk_fp8_f32(v2, v3, wrd, true);          \
            *(uint32*)&act[(RT) * 16384 + (wv * 2 + (CT)) * 1024 + pl * 32     \
                           + q * 8 + 4 * kh] = wrd;                            \
        }                                                                      \
    } while (0)

    EPI(acc00, 0, 0, b1); EPI(acc01, 0, 1, b1);
    EPI(acc10, 1, 0, b1); EPI(acc11, 1, 1, b1);
    __syncthreads();

    // ---- layers 2..5: A = weights (L2-resident panel), B = act (LDS, contiguous)
#pragma unroll
    for (int ly = 0; ly < 4; ++ly) {
        const float* bias = (ly == 0) ? b2 : (ly == 1) ? b3 : (ly == 2) ? b4 : b5;
        const u8* lyb = wt8 + ly * 262144 + wv * 32768;
        f32x16 n00 = {0.f,0.f,0.f,0.f,0.f,0.f,0.f,0.f,0.f,0.f,0.f,0.f,0.f,0.f,0.f,0.f};
        f32x16 n01 = n00, n10 = n00, n11 = n00;
#pragma unroll
        for (int kk = 0; kk < 8; ++kk) {
            int koff = (kk * 2 + kh) * 1024 + pl * 32;
            i32x8 ba0 = *(const i32x8*)&act[koff];
            i32x8 ba1 = *(const i32x8*)&act[16384 + koff];
            i32x8 aw0 = *(const i32x8*)&lyb[kk * 2048 + lane * 32];
            i32x8 aw1 = *(const i32x8*)&lyb[16384 + kk * 2048 + lane * 32];
            n00 = MFMA64(aw0, ba0, n00);
            n10 = MFMA64(aw0, ba1, n10);
            n01 = MFMA64(aw1, ba0, n01);
            n11 = MFMA64(aw1, ba1, n11);
        }
        acc00 = n00; acc01 = n01; acc10 = n10; acc11 = n11;
        __syncthreads();   // all waves done reading act
        EPI(acc00, 0, 0, bias); EPI(acc01, 0, 1, bias);
        EPI(acc10, 1, 0, bias); EPI(acc11, 1, 1, bias);
        __syncthreads();
    }

    // ---- layer 6: waves 0,1 (rt = wv), A = W6 frags (LDS), 8 K-steps
    if (wv < 2) {
        f32x16 a6 = {0.f,0.f,0.f,0.f,0.f,0.f,0.f,0.f,0.f,0.f,0.f,0.f,0.f,0.f,0.f,0.f};
#pragma unroll
        for (int kk = 0; kk < 8; ++kk) {
            i32x8 aw = *(const i32x8*)&w6lds[kk * 2048 + lane * 32];
            i32x8 ba = *(const i32x8*)&act[wv * 16384 + (kk * 2 + kh) * 1024 + pl * 32];
            a6 = MFMA64(aw, ba, a6);
        }
        int pt = wv * 32 + pl;
#pragma unroll
        for (int q = 0; q < 2; ++q) {      // rows n = q*8 + 4*kh + 0..3 (n<16 valid)
            int n0 = q * 8 + 4 * kh;
            float4 bv = *(const float4*)&b6[n0];
            swsh[pt * 17 + n0 + 0] = a6[q * 4 + 0] + bv.x;
            swsh[pt * 17 + n0 + 1] = a6[q * 4 + 1] + bv.y;
            swsh[pt * 17 + n0 + 2] = a6[q * 4 + 2] + bv.z;
            swsh[pt * 17 + n0 + 3] = a6[q * 4 + 3] + bv.w;
        }
    }
    __syncthreads();

    // ---- softmax over 16 (threads 0..63, one point each)
    if (tid < 64) {
        float zv[16];
        float m = -1e30f;
#pragma unroll
        for (int j = 0; j < 16; ++j) { zv[j] = swsh[tid * 17 + j]; m = fmaxf(m, zv[j]); }
        float s = 0.f;
#pragma unroll
        for (int j = 0; j < 16; ++j) { zv[j] = expf(zv[j] - m); s += zv[j]; }
        float inv = 1.0f / s;
#pragma unroll
        for (int j = 0; j < 16; ++j) swsh[tid * 17 + j] = zv[j] * inv;
    }
    __syncthreads();

    // ---- hash gather + weighted sum: 8 threads/point, 2 corners each
    {
        constexpr float bmin[4] = {0.0f, (float)(-PI_D), (float)(0.5 * PI_D), (float)(-0.85 * PI_D)};
        constexpr float bmax[4] = {(float)(PI_D), (float)(PI_D), (float)(0.85 * PI_D), (float)(-0.5 * PI_D)};
        constexpr uint32 primes[4] = {1u, 2654435761u, 805459861u, 3674653429u};
        const int p = tid >> 3;
        const int pr = tid & 7;
        uint32 ca[4], cb[4];
#pragma unroll
        for (int d = 0; d < 4; ++d) {
            float xv = xsh[p * 4 + d];
            float xc = fminf(fmaxf(xv, bmin[d]), bmax[d]);
            float g = (bmax[d] - bmin[d]) / res;
            float t = (xc - bmin[d]) / g;
            int bl = (int)floorf(t);
            ca[d] = (uint32)bl * primes[d];
            cb[d] = (uint32)(bl + 1) * primes[d];
        }
        float s0 = 0.f, s1 = 0.f;
        const float* tb = tables + (size_t)level * TABLE_SZ * 2;
#pragma unroll
        for (int vv = 0; vv < 2; ++vv) {
            int v = pr * 2 + vv;
            uint32 h = ((v & 8) ? cb[0] : ca[0]) ^ ((v & 4) ? cb[1] : ca[1]) ^
                       ((v & 2) ? cb[2] : ca[2]) ^ ((v & 1) ? cb[3] : ca[3]);
            float2 e = *(const float2*)(tb + (size_t)(h & HMASK) * 2);
            float wgt = swsh[p * 17 + v];
            s0 = fmaf(wgt, e.x, s0);
            s1 = fmaf(wgt, e.y, s1);
        }
#pragma unroll
        for (int sft = 1; sft < 8; sft <<= 1) {
            s0 += __shfl_xor(s0, sft, 64);
            s1 += __shfl_xor(s1, sft, 64);
        }
        if (pr == 0) {
            float* o = out + (size_t)(ptile * 64 + p) * 32 + level * 2;
            __builtin_nontemporal_store(s0, o);
            __builtin_nontemporal_store(s1, o + 1);
        }
    }
#undef EPI
}

extern "C" void kernel_launch(void* const* d_in, const int* in_sizes, int n_in,
                              void* d_out, int out_size, void* d_ws, size_t ws_size,
                              hipStream_t stream) {
    const float* x      = (const float*)d_in[0];
    const float* tables = (const float*)d_in[1];
    const float* W1 = (const float*)d_in[2];
    const float* b1 = (const float*)d_in[3];
    const float* W2 = (const float*)d_in[4];
    const float* b2 = (const float*)d_in[5];
    const float* W3 = (const float*)d_in[6];
    const float* b3 = (const float*)d_in[7];
    const float* W4 = (const float*)d_in[8];
    const float* b4 = (const float*)d_in[9];
    const float* W5 = (const float*)d_in[10];
    const float* b5 = (const float*)d_in[11];
    const float* W6 = (const float*)d_in[12];
    const float* b6 = (const float*)d_in[13];

    const int B = in_sizes[0] / 4;          // 131072
    u8* wt8 = (u8*)d_ws;                    // exactly 1 MiB fp8 panel (W2..W5)

    prep_weights<<<(NWB4 / 2 + 255) / 256, 256, 0, stream>>>(W2, W3, W4, W5, wt8);

    // ONE launch for all 16 levels: eliminates 15 per-dispatch ramp/drain pairs.
    // x walks fastest -> co-resident blocks mostly share a level (table locality).
    fused_mlp<<<dim3(NPTS / 64, 16), 512, 0, stream>>>(
        x, tables, W1, b1, wt8, W6, b2, b3, b4, b5, b6, (float*)d_out);

    mask_kernel<<<(B + 255) / 256, 256, 0, stream>>>(x, (float*)d_out + (size_t)B * 32, B);
}